// Round 15
// baseline (296.472 us; speedup 1.0000x reference)
//
#include <hip/hip_runtime.h>
#include <hip/hip_bf16.h>

#define N_ROWS 8192
#define DIM    128
#define TWO_N  16384
#define NBLK   64                         // 256-row/col block stripes
#define NTRI   (NBLK * (NBLK + 1) / 2)    // 2080 triangular blocks
#define EXP_TWO 7.38905609893065f
// sqrt(2 * log2(e)): folding exp(2*dot) == exp2(SCALE^2 * dot) into the operands
#define H_SCALE 1.6986436f

typedef __attribute__((ext_vector_type(8))) short short8;
typedef __attribute__((ext_vector_type(4))) float float4v;

__device__ inline void async_copy16(const void* g, void* l) {
  __builtin_amdgcn_global_load_lds(
      (const __attribute__((address_space(1))) void*)g,
      (__attribute__((address_space(3))) void*)l, 16, 0, 0);
}

__device__ inline float fast_exp2(float x) {
#if __has_builtin(__builtin_amdgcn_exp2f)
  return __builtin_amdgcn_exp2f(x);
#else
  return exp2f(x);
#endif
}

// ---------------------------------------------------------------------------
// Blocked H layout, lane-sequential chunk order (16x16x32 fragments):
//   element (row,k) -> tile T=row>>4, Kt=k>>5 ;
//   chunk-in-tile = ((k&31)>>3)*16 + (row&15)   (== MFMA lane q*16+m)
//   short addr = (T*4 + Kt)*512 + chunk*8 + (k&7)
// ---------------------------------------------------------------------------

// ---------------------------------------------------------------------------
// Kernel 1: unchanged from R9.
// ---------------------------------------------------------------------------
__global__ __launch_bounds__(256) void norm_kernel(
    const float* __restrict__ h1, const float* __restrict__ h2,
    __hip_bfloat16* __restrict__ Hb, float* __restrict__ posdot,
    float* __restrict__ rowsum) {
  if (threadIdx.x < 8) rowsum[blockIdx.x * 8 + threadIdx.x] = 0.0f;

  int lane = threadIdx.x & 63;
  int w    = threadIdx.x >> 6;
  int row  = blockIdx.x * 4 + w;                  // 0..8191

  const float2* p1 = (const float2*)(h1 + (size_t)row * DIM);
  const float2* p2 = (const float2*)(h2 + (size_t)row * DIM);
  float2 v1 = p1[lane];
  float2 v2 = p2[lane];

  float ss1 = v1.x * v1.x + v1.y * v1.y;
  float ss2 = v2.x * v2.x + v2.y * v2.y;
  #pragma unroll
  for (int s = 32; s; s >>= 1) {
    ss1 += __shfl_xor(ss1, s);
    ss2 += __shfl_xor(ss2, s);
  }
  float inv1 = 1.0f / fmaxf(sqrtf(ss1), 1e-12f);
  float inv2 = 1.0f / fmaxf(sqrtf(ss2), 1e-12f);

  float ax = v1.x * inv1, ay = v1.y * inv1;
  float bx = v2.x * inv2, by = v2.y * inv2;

  float pd = ax * bx + ay * by;       // exact fp32 posdot (unscaled)
  #pragma unroll
  for (int s = 32; s; s >>= 1) pd += __shfl_xor(pd, s);

  int Kt = lane >> 4, q8 = (lane & 15) >> 2, sic = (lane & 3) * 2;
  short* Hs = (short*)Hb;
  {
    int r1 = row;
    size_t off = (size_t)((r1 >> 4) * 4 + Kt) * 512 + (q8 * 16 + (r1 & 15)) * 8 + sic;
    __hip_bfloat162 t;
    t.x = __float2bfloat16(ax * H_SCALE); t.y = __float2bfloat16(ay * H_SCALE);
    *(__hip_bfloat162*)(Hs + off) = t;
  }
  {
    int r2 = row + N_ROWS;
    size_t off = (size_t)((r2 >> 4) * 4 + Kt) * 512 + (q8 * 16 + (r2 & 15)) * 8 + sic;
    __hip_bfloat162 t;
    t.x = __float2bfloat16(bx * H_SCALE); t.y = __float2bfloat16(by * H_SCALE);
    *(__hip_bfloat162*)(Hs + off) = t;
  }

  if (lane == 0) posdot[row] = pd;
}

// ---------------------------------------------------------------------------
// Kernel 2 ABLATION (R15, diagnostic): V0 = R9 verbatim (59us best, real
// output). V1-V4 stub exactly one phase each, write to scratch:
//   V1: no exp2 (e = acc[i])            -> trans-pipe cost
//   V2: b hoisted, no per-subtile dsread -> LDS-read pipe cost
//   V3: no MFMA (b kept live via asm)    -> MFMA pipe cost
//   V4: no panel staging                 -> staging/L2 cost
// asm keepalives prevent DCE of upstream ops (learn_hip rule #17).
// NOTE (R5-R7): no device fence. (R11): no block split. (R12/R14): no
// schedule machinery. (R10/R13): 32 rows/wave sweet spot.
// ---------------------------------------------------------------------------
template <int V>
__global__ __launch_bounds__(512, 2) void ntx_main(
    const __hip_bfloat16* __restrict__ Hb, float* __restrict__ rowsum) {
  __shared__ short smem[32768];       // 64 KB: full B panel, blocked order
  __shared__ float colacc[8][256];    // 8 KB: per-wave col-sum slices
  const short* H = (const short*)Hb;

  int tid  = threadIdx.x;
  int lane = tid & 63;
  int w    = tid >> 6;      // 0..7
  int q    = lane >> 4;     // k-chunk selector within fragment
  int m    = lane & 15;     // row-within-subtile / col-within-subtile

  // Triangular decode: blockIdx.x -> (I, J) with J >= I over NBLK stripes.
  int t0 = blockIdx.x;
  int I = (int)((129.0f - sqrtf(129.0f * 129.0f - 8.0f * (float)t0)) * 0.5f);
  while ((I + 1) * (129 - (I + 1)) / 2 <= t0) ++I;   // fixup fp rounding
  while (I * (129 - I) / 2 > t0) --I;
  int J = I + (t0 - I * (129 - I) / 2);
  bool diag = (I == J);

  // Stage the full B panel (stripe J, 64 KB contiguous) into LDS, linearly.
  const short* gpanel = H + (size_t)J * 32768;
  if (V != 4) {
    #pragma unroll
    for (int it = 0; it < 8; ++it)
      async_copy16(gpanel + it * 4096 + tid * 8, (void*)&smem[it * 4096 + tid * 8]);
  }

  // A fragments: 2 row-subtiles x 4 k-steps, blocked-layout loads, pinned.
  short8 a[2][4];
  #pragma unroll
  for (int r = 0; r < 2; ++r)
    #pragma unroll
    for (int s = 0; s < 4; ++s)
      a[r][s] = *(const short8*)(H + (size_t)((I * 16 + w * 2 + r) * 4 + s) * 512 + lane * 8);
  #pragma unroll
  for (int r = 0; r < 2; ++r)
    #pragma unroll
    for (int s = 0; s < 4; ++s)
      asm volatile("" : "+v"(a[r][s]));

  float rowacc[2][4];
  #pragma unroll
  for (int r = 0; r < 2; ++r)
    #pragma unroll
    for (int i = 0; i < 4; ++i) rowacc[r][i] = 0.0f;

  __syncthreads();   // single staging barrier (drains vmcnt for the panel)

  short8 bh[4];      // V2: b fragments hoisted out of the subtile loop
  if (V == 2) {
    #pragma unroll
    for (int s = 0; s < 4; ++s)
      bh[s] = *(const short8*)&smem[s * 512 + lane * 8];
    #pragma unroll
    for (int s = 0; s < 4; ++s)
      asm volatile("" : "+v"(bh[s]));
  }

  // Barrier-free compute: 16 subtiles from LDS.
  #pragma unroll 4
  for (int cs = 0; cs < 16; ++cs) {
    short8 b[4];
    if (V == 2) {
      #pragma unroll
      for (int s = 0; s < 4; ++s) b[s] = bh[s];
    } else {
      #pragma unroll
      for (int s = 0; s < 4; ++s)
        b[s] = *(const short8*)&smem[cs * 2048 + s * 512 + lane * 8];
    }
    if (V == 3) {
      // keep the ds_reads live without feeding MFMA
      asm volatile("" :: "v"(b[0]), "v"(b[1]), "v"(b[2]), "v"(b[3]));
    }
    float cp = 0.0f;
    #pragma unroll
    for (int r = 0; r < 2; ++r) {
      float4v acc = {0.f, 0.f, 0.f, 0.f};
      if (V != 3) {
        #pragma unroll
        for (int s = 0; s < 4; ++s)
          acc = __builtin_amdgcn_mfma_f32_16x16x32_bf16(a[r][s], b[s], acc, 0, 0, 0);
      }
      #pragma unroll
      for (int i = 0; i < 4; ++i) {
        float e = (V == 1) ? acc[i] : fast_exp2(acc[i]);
        rowacc[r][i] += e;
        cp += e;
      }
    }
    if (!diag) {
      cp += __shfl_xor(cp, 16);
      cp += __shfl_xor(cp, 32);
      if (q == 0) colacc[w][cs * 16 + m] = cp;
    }
  }

  // Row sums: reduce across the 16 column-lanes holding the same rows.
  int rowbase = I * 256 + w * 32;
  #pragma unroll
  for (int r = 0; r < 2; ++r)
    #pragma unroll
    for (int i = 0; i < 4; ++i) {
      float v = rowacc[r][i];
      v += __shfl_xor(v, 1);
      v += __shfl_xor(v, 2);
      v += __shfl_xor(v, 4);
      v += __shfl_xor(v, 8);
      rowacc[r][i] = v;
    }
  if (m == 0) {
    #pragma unroll
    for (int r = 0; r < 2; ++r)
      #pragma unroll
      for (int i = 0; i < 4; ++i)
        atomicAdd(&rowsum[rowbase + r * 16 + q * 4 + i], rowacc[r][i]);
  }

  // Col sums -> stripe J (symmetric contribution).
  if (!diag) {
    __syncthreads();
    if (tid < 256) {
      float v = 0.0f;
      #pragma unroll
      for (int ww = 0; ww < 8; ++ww) v += colacc[ww][tid];
      atomicAdd(&rowsum[J * 256 + tid], v);
    }
  }
}

// ---------------------------------------------------------------------------
// Kernel 3: unchanged from R9.
// ---------------------------------------------------------------------------
__global__ __launch_bounds__(1024) void finalize(
    const float* __restrict__ rowsum, const float* __restrict__ posdot,
    float* __restrict__ out) {
  __shared__ float red[32];
  int tid = threadIdx.x;
  const float4* rs4 = (const float4*)rowsum;
  const float4* pd4 = (const float4*)posdot;
  float ld = 0.0f, pp = 0.0f;
  #pragma unroll
  for (int it = 0; it < 4; ++it) {
    float4 v = rs4[tid + it * 1024];
    ld += logf(v.x - EXP_TWO) + logf(v.y - EXP_TWO) +
          logf(v.z - EXP_TWO) + logf(v.w - EXP_TWO);
  }
  #pragma unroll
  for (int it = 0; it < 2; ++it) {
    float4 v = pd4[tid + it * 1024];
    pp += v.x + v.y + v.z + v.w;
  }
  #pragma unroll
  for (int s = 32; s; s >>= 1) {
    ld += __shfl_xor(ld, s);
    pp += __shfl_xor(pp, s);
  }
  if ((tid & 63) == 0) {
    red[tid >> 6] = ld;
    red[16 + (tid >> 6)] = pp;
  }
  __syncthreads();
  if (tid == 0) {
    float tl = 0.0f, tp = 0.0f;
    #pragma unroll
    for (int i = 0; i < 16; ++i) { tl += red[i]; tp += red[16 + i]; }
    *out = (tl - 4.0f * tp) / (float)TWO_N;
  }
}

extern "C" void kernel_launch(void* const* d_in, const int* in_sizes, int n_in,
                              void* d_out, int out_size, void* d_ws, size_t ws_size,
                              hipStream_t stream) {
  const float* h1 = (const float*)d_in[0];
  const float* h2 = (const float*)d_in[1];
  char* ws = (char*)d_ws;

  __hip_bfloat16* Hb = (__hip_bfloat16*)ws;                       // 4 MB (blocked)
  float* rowsum      = (float*)(ws + 4194304);                    // 64 KB
  float* posdot      = (float*)(ws + 4194304 + 65536);            // 32 KB
  float* rowsum_scr  = (float*)(ws + 4194304 + 65536 + 32768);    // 64 KB scratch
  float* out         = (float*)d_out;

  norm_kernel<<<N_ROWS / 4, 256, 0, stream>>>(h1, h2, Hb, posdot, rowsum);
  ntx_main<0><<<NTRI, 512, 0, stream>>>(Hb, rowsum);       // real result
  ntx_main<1><<<NTRI, 512, 0, stream>>>(Hb, rowsum_scr);   // no exp2
  ntx_main<2><<<NTRI, 512, 0, stream>>>(Hb, rowsum_scr);   // no per-subtile dsread
  ntx_main<3><<<NTRI, 512, 0, stream>>>(Hb, rowsum_scr);   // no MFMA
  ntx_main<4><<<NTRI, 512, 0, stream>>>(Hb, rowsum_scr);   // no staging
  finalize<<<1, 1024, 0, stream>>>(rowsum, posdot, out);
}

// Round 16
// 117.236 us; speedup vs baseline: 2.5289x; 2.5289x over previous
//
#include <hip/hip_runtime.h>
#include <hip/hip_bf16.h>

#define N_ROWS 8192
#define DIM    128
#define TWO_N  16384
#define NBLK   64                         // 256-row/col block stripes
#define NTRI   (NBLK * (NBLK + 1) / 2)    // 2080 triangular blocks
#define EXP_TWO 7.38905609893065f
// sqrt(2 * log2(e)): folding exp(2*dot) == exp2(SCALE^2 * dot) into the operands
#define H_SCALE 1.6986436f

typedef __attribute__((ext_vector_type(8))) short short8;
typedef __attribute__((ext_vector_type(4))) float float4v;

__device__ inline void async_copy16(const void* g, void* l) {
  __builtin_amdgcn_global_load_lds(
      (const __attribute__((address_space(1))) void*)g,
      (__attribute__((address_space(3))) void*)l, 16, 0, 0);
}

__device__ inline float fast_exp2(float x) {
#if __has_builtin(__builtin_amdgcn_exp2f)
  return __builtin_amdgcn_exp2f(x);
#else
  return exp2f(x);
#endif
}

// ---------------------------------------------------------------------------
// Blocked H layout, lane-sequential chunk order (16x16x32 fragments):
//   element (row,k) -> tile T=row>>4, Kt=k>>5 ;
//   chunk-in-tile = ((k&31)>>3)*16 + (row&15)   (== MFMA lane q*16+m)
//   short addr = (T*4 + Kt)*512 + chunk*8 + (k&7)
// A row-tile T's 4 K-tiles are one contiguous 4KB region at T*2048 shorts.
// ---------------------------------------------------------------------------

// ---------------------------------------------------------------------------
// Kernel 1 (R16 rewrite): one block per 16-row tile; thread tid covers
// row=tid>>4, 8 consecutive k at kc=tid&15. Row reductions over the 16
// contiguous lanes per row. The blocked-layout destination of this thread's
// 8 bf16 is chunk L=(kc>>2)*64+(kc&3)*16+row of the tile's contiguous 4KB
// -> one 16B store per matrix, line-coalesced (each 64B line = 4 lanes of
// one wave). Replaces the old 64-lane x 4B scatter (G13 anti-pattern).
// posdot = dot * inv1 * inv2 (same value, reassociated).
// ---------------------------------------------------------------------------
__global__ __launch_bounds__(256) void norm_kernel(
    const float* __restrict__ h1, const float* __restrict__ h2,
    __hip_bfloat16* __restrict__ Hb, float* __restrict__ posdot,
    float* __restrict__ rowsum) {
  int tid = threadIdx.x;
  int T   = blockIdx.x;                 // row-tile 0..511
  if (tid < 32) rowsum[T * 32 + tid] = 0.0f;

  int row  = tid >> 4;                  // 0..15 within tile
  int kc   = tid & 15;                  // 8-float k-chunk
  int grow = T * 16 + row;

  const float4* p1 = (const float4*)(h1 + (size_t)grow * DIM + kc * 8);
  const float4* p2 = (const float4*)(h2 + (size_t)grow * DIM + kc * 8);
  float4 u0 = p1[0], u1 = p1[1];
  float4 v0 = p2[0], v1 = p2[1];

  float ss1 = u0.x*u0.x + u0.y*u0.y + u0.z*u0.z + u0.w*u0.w
            + u1.x*u1.x + u1.y*u1.y + u1.z*u1.z + u1.w*u1.w;
  float ss2 = v0.x*v0.x + v0.y*v0.y + v0.z*v0.z + v0.w*v0.w
            + v1.x*v1.x + v1.y*v1.y + v1.z*v1.z + v1.w*v1.w;
  float dp  = u0.x*v0.x + u0.y*v0.y + u0.z*v0.z + u0.w*v0.w
            + u1.x*v1.x + u1.y*v1.y + u1.z*v1.z + u1.w*v1.w;

  // reduce across the 16 lanes of this row (masks < 16 stay in-group)
  #pragma unroll
  for (int s = 1; s < 16; s <<= 1) {
    ss1 += __shfl_xor(ss1, s);
    ss2 += __shfl_xor(ss2, s);
    dp  += __shfl_xor(dp, s);
  }
  float inv1 = 1.0f / fmaxf(sqrtf(ss1), 1e-12f);
  float inv2 = 1.0f / fmaxf(sqrtf(ss2), 1e-12f);
  if (kc == 0) posdot[grow] = dp * inv1 * inv2;

  float s1 = inv1 * H_SCALE, s2 = inv2 * H_SCALE;
  short8 o1, o2;
  o1[0] = (short)__bfloat16_as_ushort(__float2bfloat16(u0.x * s1));
  o1[1] = (short)__bfloat16_as_ushort(__float2bfloat16(u0.y * s1));
  o1[2] = (short)__bfloat16_as_ushort(__float2bfloat16(u0.z * s1));
  o1[3] = (short)__bfloat16_as_ushort(__float2bfloat16(u0.w * s1));
  o1[4] = (short)__bfloat16_as_ushort(__float2bfloat16(u1.x * s1));
  o1[5] = (short)__bfloat16_as_ushort(__float2bfloat16(u1.y * s1));
  o1[6] = (short)__bfloat16_as_ushort(__float2bfloat16(u1.z * s1));
  o1[7] = (short)__bfloat16_as_ushort(__float2bfloat16(u1.w * s1));
  o2[0] = (short)__bfloat16_as_ushort(__float2bfloat16(v0.x * s2));
  o2[1] = (short)__bfloat16_as_ushort(__float2bfloat16(v0.y * s2));
  o2[2] = (short)__bfloat16_as_ushort(__float2bfloat16(v0.z * s2));
  o2[3] = (short)__bfloat16_as_ushort(__float2bfloat16(v0.w * s2));
  o2[4] = (short)__bfloat16_as_ushort(__float2bfloat16(v1.x * s2));
  o2[5] = (short)__bfloat16_as_ushort(__float2bfloat16(v1.y * s2));
  o2[6] = (short)__bfloat16_as_ushort(__float2bfloat16(v1.z * s2));
  o2[7] = (short)__bfloat16_as_ushort(__float2bfloat16(v1.w * s2));

  // chunk index within the tile's contiguous 4KB region
  int L = (kc >> 2) * 64 + (kc & 3) * 16 + row;
  short* Hs = (short*)Hb;
  *(short8*)(Hs + (size_t)T * 2048 + L * 8) = o1;               // h1 tile T
  *(short8*)(Hs + (size_t)(512 + T) * 2048 + L * 8) = o2;       // h2 tile 512+T
}

// ---------------------------------------------------------------------------
// Kernel 2: row sums of exp2(H H^T), upper block-triangle only (symmetry).
// R9 VERBATIM (59us best). R15 ablation: no single phase dominates — the
// block runs as a serialized pipe-sum (staging+LDS+VALU+exp+MFMA each 0.5-3
// us/block-slot); this structure is at its serial floor.
// NOTE (R5-R7): no device fence. (R11): no block split. (R12/R14): no
// schedule machinery. (R10/R13): 32 rows/wave sweet spot.
// ---------------------------------------------------------------------------
__global__ __launch_bounds__(512, 2) void ntx_main(
    const __hip_bfloat16* __restrict__ Hb, float* __restrict__ rowsum) {
  __shared__ short smem[32768];       // 64 KB: full B panel, blocked order
  __shared__ float colacc[8][256];    // 8 KB: per-wave col-sum slices
  const short* H = (const short*)Hb;

  int tid  = threadIdx.x;
  int lane = tid & 63;
  int w    = tid >> 6;      // 0..7
  int q    = lane >> 4;     // k-chunk selector within fragment
  int m    = lane & 15;     // row-within-subtile / col-within-subtile

  // Triangular decode: blockIdx.x -> (I, J) with J >= I over NBLK stripes.
  int t0 = blockIdx.x;
  int I = (int)((129.0f - sqrtf(129.0f * 129.0f - 8.0f * (float)t0)) * 0.5f);
  while ((I + 1) * (129 - (I + 1)) / 2 <= t0) ++I;   // fixup fp rounding
  while (I * (129 - I) / 2 > t0) --I;
  int J = I + (t0 - I * (129 - I) / 2);
  bool diag = (I == J);

  // Stage the full B panel (stripe J, 64 KB contiguous) into LDS, linearly.
  const short* gpanel = H + (size_t)J * 32768;
  #pragma unroll
  for (int it = 0; it < 8; ++it)
    async_copy16(gpanel + it * 4096 + tid * 8, (void*)&smem[it * 4096 + tid * 8]);

  // A fragments: 2 row-subtiles x 4 k-steps, blocked-layout loads, pinned.
  short8 a[2][4];
  #pragma unroll
  for (int r = 0; r < 2; ++r)
    #pragma unroll
    for (int s = 0; s < 4; ++s)
      a[r][s] = *(const short8*)(H + (size_t)((I * 16 + w * 2 + r) * 4 + s) * 512 + lane * 8);
  #pragma unroll
  for (int r = 0; r < 2; ++r)
    #pragma unroll
    for (int s = 0; s < 4; ++s)
      asm volatile("" : "+v"(a[r][s]));

  float rowacc[2][4];
  #pragma unroll
  for (int r = 0; r < 2; ++r)
    #pragma unroll
    for (int i = 0; i < 4; ++i) rowacc[r][i] = 0.0f;

  __syncthreads();   // single staging barrier (drains vmcnt for the panel)

  // Barrier-free compute: 16 subtiles from LDS.
  #pragma unroll 4
  for (int cs = 0; cs < 16; ++cs) {
    short8 b[4];
    #pragma unroll
    for (int s = 0; s < 4; ++s)
      b[s] = *(const short8*)&smem[cs * 2048 + s * 512 + lane * 8];
    float cp = 0.0f;
    #pragma unroll
    for (int r = 0; r < 2; ++r) {
      float4v acc = {0.f, 0.f, 0.f, 0.f};
      #pragma unroll
      for (int s = 0; s < 4; ++s)
        acc = __builtin_amdgcn_mfma_f32_16x16x32_bf16(a[r][s], b[s], acc, 0, 0, 0);
      #pragma unroll
      for (int i = 0; i < 4; ++i) {
        float e = fast_exp2(acc[i]);   // acc already = 2*log2e*dot
        rowacc[r][i] += e;
        cp += e;
      }
    }
    if (!diag) {
      // sum over the 4 q-groups -> col sum over this wave's 32 rows
      cp += __shfl_xor(cp, 16);
      cp += __shfl_xor(cp, 32);
      if (q == 0) colacc[w][cs * 16 + m] = cp;
    }
  }

  // Row sums: reduce across the 16 column-lanes holding the same rows.
  int rowbase = I * 256 + w * 32;
  #pragma unroll
  for (int r = 0; r < 2; ++r)
    #pragma unroll
    for (int i = 0; i < 4; ++i) {
      float v = rowacc[r][i];
      v += __shfl_xor(v, 1);
      v += __shfl_xor(v, 2);
      v += __shfl_xor(v, 4);
      v += __shfl_xor(v, 8);
      rowacc[r][i] = v;
    }
  if (m == 0) {
    #pragma unroll
    for (int r = 0; r < 2; ++r)
      #pragma unroll
      for (int i = 0; i < 4; ++i)
        atomicAdd(&rowsum[rowbase + r * 16 + q * 4 + i], rowacc[r][i]);
  }

  // Col sums -> stripe J (symmetric contribution).
  if (!diag) {
    __syncthreads();
    if (tid < 256) {
      float v = 0.0f;
      #pragma unroll
      for (int ww = 0; ww < 8; ++ww) v += colacc[ww][tid];
      atomicAdd(&rowsum[J * 256 + tid], v);
    }
  }
}

// ---------------------------------------------------------------------------
// Kernel 3: loss = ( sum_i log(rowsum_i - e^2) - 4 * sum_i posdot_i ) / 2N
// float4 loads + 4 independent logf per iter to break the dependent chain.
// ---------------------------------------------------------------------------
__global__ __launch_bounds__(1024) void finalize(
    const float* __restrict__ rowsum, const float* __restrict__ posdot,
    float* __restrict__ out) {
  __shared__ float red[32];
  int tid = threadIdx.x;
  const float4* rs4 = (const float4*)rowsum;
  const float4* pd4 = (const float4*)posdot;
  float ld = 0.0f, pp = 0.0f;
  #pragma unroll
  for (int it = 0; it < 4; ++it) {
    float4 v = rs4[tid + it * 1024];
    ld += logf(v.x - EXP_TWO) + logf(v.y - EXP_TWO) +
          logf(v.z - EXP_TWO) + logf(v.w - EXP_TWO);
  }
  #pragma unroll
  for (int it = 0; it < 2; ++it) {
    float4 v = pd4[tid + it * 1024];
    pp += v.x + v.y + v.z + v.w;
  }
  #pragma unroll
  for (int s = 32; s; s >>= 1) {
    ld += __shfl_xor(ld, s);
    pp += __shfl_xor(pp, s);
  }
  if ((tid & 63) == 0) {
    red[tid >> 6] = ld;
    red[16 + (tid >> 6)] = pp;
  }
  __syncthreads();
  if (tid == 0) {
    float tl = 0.0f, tp = 0.0f;
    #pragma unroll
    for (int i = 0; i < 16; ++i) { tl += red[i]; tp += red[16 + i]; }
    *out = (tl - 4.0f * tp) / (float)TWO_N;
  }
}

extern "C" void kernel_launch(void* const* d_in, const int* in_sizes, int n_in,
                              void* d_out, int out_size, void* d_ws, size_t ws_size,
                              hipStream_t stream) {
  const float* h1 = (const float*)d_in[0];
  const float* h2 = (const float*)d_in[1];
  char* ws = (char*)d_ws;

  __hip_bfloat16* Hb = (__hip_bfloat16*)ws;                       // 4 MB (blocked)
  float* rowsum      = (float*)(ws + 4194304);                    // 64 KB
  float* posdot      = (float*)(ws + 4194304 + 65536);            // 32 KB
  float* out         = (float*)d_out;

  norm_kernel<<<512, 256, 0, stream>>>(h1, h2, Hb, posdot, rowsum);
  ntx_main<<<NTRI, 512, 0, stream>>>(Hb, rowsum);
  finalize<<<1, 1024, 0, stream>>>(rowsum, posdot, out);
}